// Round 21
// baseline (811.888 us; speedup 1.0000x reference)
//
#include <hip/hip_runtime.h>

// RGCN 3-layer forward, MI355X — decoupled aggregate-then-transform v15 (chunked).
// Identity: sum_e x[src_e] @ W_r == (sum_e x[src_e]) @ W_r.
// r13-r19 postmortems: agg FETCH 225MB/pass = x re-fetched because the 205MB Y
// write stream evicts it from L3; Y then re-read from HBM by gemm. v15: process
// each layer in dst-chunks of CT=512 tiles, agg(chunk)->gemm(chunk), with ONE
// 67MB Y buffer reused across chunks: gemm reads Y L3-hot, the next chunk
// re-dirties the same lines before writeback (Y HBM traffic ~67MB/run instead
// of 615MB), and x+Y-chunk fit L3 together so the gather stops missing.
// Chunking needs ping-pong x buffers (in-place would race across chunks).
// r20 was a host/device compile bug (imin in host lambda) — fixed via hmin.

#define DEVI __device__ __forceinline__

typedef __attribute__((ext_vector_type(8))) short bf16x8;
typedef __attribute__((ext_vector_type(4))) float f32x4;

DEVI unsigned short f2b(float f) {
  unsigned int u = __builtin_bit_cast(unsigned int, f);
  unsigned int r = (u + 0x7FFFu + ((u >> 16) & 1u)) >> 16;
  return (unsigned short)r;
}
DEVI float b2f(unsigned short h) {
  unsigned int u = ((unsigned int)h) << 16;
  return __builtin_bit_cast(float, u);
}
DEVI float lo16f(unsigned v) { return __builtin_bit_cast(float, v << 16); }
DEVI float hifraw(unsigned v) { return __builtin_bit_cast(float, v); }  // hi bf16 + low-bit dust (<0.45% rel)
DEVI int imin(int a, int b) { return a < b ? a : b; }
DEVI int imax(int a, int b) { return a > b ? a : b; }
static inline int hmin(int a, int b) { return a < b ? a : b; }

// ---------------- sort v5: coarse bins = rel*NG + (tile>>7) ----------------

__global__ void k_zero2(int* __restrict__ cnt, int n) {
  int stride = gridDim.x * blockDim.x;
  for (int i = blockIdx.x * blockDim.x + threadIdx.x; i < n; i += stride) cnt[i] = 0;
}

__global__ void k_chist(const int* __restrict__ et, const int* __restrict__ edst,
                        int* __restrict__ gh, int NG, int E) {
  __shared__ int h[128];
  if (threadIdx.x < 128) h[threadIdx.x] = 0;
  __syncthreads();
  int stride = gridDim.x * blockDim.x;
  for (int i = blockIdx.x * blockDim.x + threadIdx.x; i < E; i += stride)
    atomicAdd(&h[(et[i] & 7) * NG + (edst[i] >> 13)], 1);
  __syncthreads();
  if (threadIdx.x < 128) atomicAdd(&gh[threadIdx.x], h[threadIdx.x]);
}

__global__ void k_cscan(const int* __restrict__ gh, int* __restrict__ gcursor,
                        int* __restrict__ cbase, int NBC, int E) {
  if (threadIdx.x == 0) {
    int a = 0;
    for (int b = 0; b < NBC; ++b) { cbase[b] = a; gcursor[b] = a; a += gh[b]; }
    cbase[NBC] = E;
  }
}

__launch_bounds__(256)
__global__ void k_cfill(const int* __restrict__ et, const int* __restrict__ esrc,
                        const int* __restrict__ edst, int* __restrict__ gcursor,
                        int* __restrict__ stage, int NG, int E) {
  __shared__ int h[128], base[128], lc[128];
  int nb = gridDim.x;
  int slice = (E + nb - 1) / nb;
  int lo = blockIdx.x * slice;
  int hi = lo + slice < E ? lo + slice : E;
  int t = threadIdx.x;
  if (t < 128) { h[t] = 0; lc[t] = 0; }
  __syncthreads();
  for (int i = lo + t; i < hi; i += 256)
    atomicAdd(&h[(et[i] & 7) * NG + (edst[i] >> 13)], 1);
  __syncthreads();
  if (t < 128 && h[t] > 0) base[t] = atomicAdd(&gcursor[t], h[t]);
  __syncthreads();
  for (int i = lo + t; i < hi; i += 256) {
    int d = edst[i];
    int tile = d >> 6;
    int bin = (et[i] & 7) * NG + (tile >> 7);
    int p = base[bin] + atomicAdd(&lc[bin], 1);
    stage[p] = ((tile & 127) << 23) | ((d & 63) << 17) | esrc[i];
  }
}

__launch_bounds__(1024)
__global__ void k_fine(const int* __restrict__ cbase, const int* __restrict__ stage,
                       int* __restrict__ srcl, int* __restrict__ lo9,
                       int* __restrict__ len9, int NG, int NTr) {
  __shared__ int h[8192];
  __shared__ int tsum[1024];
  __shared__ int wsum[16];
  int b = blockIdx.x;
  int rel = b / NG, tg = b - rel * NG;
  int lo = cbase[b], hi = cbase[b + 1];
  int t = threadIdx.x;
  for (int k = t; k < 8192; k += 1024) h[k] = 0;
  __syncthreads();
  for (int i = lo + t; i < hi; i += 1024)
    atomicAdd(&h[(stage[i] >> 17) & 0x1FFF], 1);
  __syncthreads();
  int dbase = tg * 8192;
  size_t relbase = (size_t)rel * NTr;
  for (int k = t; k < 8192; k += 1024) {
    int d = dbase + k;
    if (d < NTr) len9[relbase + d] = h[k];
  }
  int loc[8];
  int s = 0;
  int kb = t * 8;
#pragma unroll
  for (int j = 0; j < 8; ++j) { loc[j] = s; s += h[kb + j]; }
  tsum[t] = s;
  __syncthreads();
  int lane = t & 63, w = t >> 6;
  int v = tsum[t];
#pragma unroll
  for (int o = 1; o < 64; o <<= 1) {
    int u = __shfl_up(v, o);
    if (lane >= o) v += u;
  }
  if (lane == 63) wsum[w] = v;
  __syncthreads();
  if (t == 0) {
    int a = 0;
#pragma unroll
    for (int j = 0; j < 16; ++j) { int tmp = wsum[j]; wsum[j] = a; a += tmp; }
  }
  __syncthreads();
  int texcl = v - s + wsum[w];
#pragma unroll
  for (int j = 0; j < 8; ++j) h[kb + j] = texcl + loc[j];
  __syncthreads();
  for (int k = t; k < 8192; k += 1024) {
    int d = dbase + k;
    if (d < NTr) lo9[relbase + d] = lo + h[k];
  }
  __syncthreads();
  for (int i = lo + t; i < hi; i += 1024) {
    int pk = stage[i];
    int key = (pk >> 17) & 0x1FFF;
    int p = atomicAdd(&h[key], 1);
    srcl[lo + p] = pk & 0x1FFFF;
  }
}

// ---------------- weight prep: fp32 [9][128][DOUT] -> bf16 [9][DOUT][128] ----------------

__global__ void wprep_kernel(const float* __restrict__ Wrel, const float* __restrict__ Wroot,
                             unsigned short* __restrict__ wt, int DOUT) {
  int total = 9 * 128 * DOUT;
  int stride = gridDim.x * blockDim.x;
  for (int i = blockIdx.x * blockDim.x + threadIdx.x; i < total; i += stride) {
    int k = i & 127;
    int oo = i >> 7;
    int o = oo % DOUT;
    int rr = oo / DOUT;
    float v = (rr < 8) ? Wrel[((size_t)rr * 128 + k) * DOUT + o]
                       : Wroot[(size_t)k * DOUT + o];
    wt[i] = f2b(v);
  }
}

// ---------------- aggregation (chunked): Y[dl] slice r = sum seg(r, d) x[src] ----
// 1 wave per dst row within the chunk; 8 rels statically unrolled; first-4
// edges prefetched unconditionally with self-clamped indices.

__launch_bounds__(256)
__global__ void agg_kernel(const unsigned* __restrict__ x32,   // [NTr][64] dwords
                           const int* __restrict__ lo9, const int* __restrict__ len9,
                           const int* __restrict__ srcl,
                           unsigned* __restrict__ Ydw,         // [CT*64][512] dwords
                           int N, int E, int NTr, int row0) {
  constexpr int NRP = 8;
  int lane = threadIdx.x & 63;
  int dl = (blockIdx.x * blockDim.x + threadIdx.x) >> 6;   // chunk-local row
  int d = row0 + dl;
  if (d >= N) return;

  int lo[NRP], ln[NRP];
#pragma unroll
  for (int r = 0; r < NRP; ++r) {
    size_t idx = (size_t)r * NTr + d;
    lo[r] = lo9[idx];
    ln[r] = len9[idx];
  }

  int s[NRP][4];
#pragma unroll
  for (int r = 0; r < NRP; ++r) {
    int lo_c = imin(lo[r], E - 1);
    int jmax = imax(ln[r] - 1, 0);
#pragma unroll
    for (int j = 0; j < 4; ++j)
      s[r][j] = srcl[lo_c + imin(j, jmax)];
  }

  unsigned v[NRP][4];
#pragma unroll
  for (int r = 0; r < NRP; ++r)
#pragma unroll
    for (int j = 0; j < 4; ++j)
      v[r][j] = x32[(size_t)s[r][j] * 64 + lane];

#pragma unroll
  for (int r = 0; r < NRP; ++r) {
    float a0 = 0.f, a1 = 0.f;
#pragma unroll
    for (int j = 0; j < 4; ++j) {
      if (ln[r] > j) { a0 += lo16f(v[r][j]); a1 += hifraw(v[r][j]); }
    }
    if (ln[r] > 4) {
      int i = lo[r] + 4, e = lo[r] + ln[r];
      for (; i + 2 <= e; i += 2) {
        int sA = srcl[i], sB = srcl[i + 1];
        unsigned vA = x32[(size_t)sA * 64 + lane];
        unsigned vB = x32[(size_t)sB * 64 + lane];
        a0 += lo16f(vA) + lo16f(vB);
        a1 += hifraw(vA) + hifraw(vB);
      }
      if (i < e) {
        unsigned vA = x32[(size_t)srcl[i] * 64 + lane];
        a0 += lo16f(vA);
        a1 += hifraw(vA);
      }
    }
    Ydw[(size_t)dl * 512 + r * 64 + lane] =
        (unsigned)f2b(a0) | ((unsigned)f2b(a1) << 16);
  }
}

// ---------------- LDS-staged GEMM, col-split waves, chunked ----------------

struct SrcArr {
  const unsigned short* a[9];
  const unsigned short* w[9];
  int st[9];
  int ro[9];     // row offset subtracted before indexing (chunk-local buffers)
};

// EPI: 3=bias+relu->bf16; 4=bias+lsm->f32
template <int DOUT, int EPI>
__launch_bounds__(256)
__global__ void gemm_lds(SrcArr S, const float* __restrict__ bias,
                         unsigned short* __restrict__ out_b,
                         float* __restrict__ out_f, int N, int c0) {
  constexpr int NK = 9;
  __shared__ unsigned short Al[2][64 * 128];
  constexpr int NF = (DOUT == 128) ? 2 : 1;
  int tid = threadIdx.x, wid = tid >> 6, lane = tid & 63;
  int colb = lane & 15, kgrp = lane >> 4;
  int colw = wid * 16 * NF;
  int tile = c0 + (gridDim.x - 1 - blockIdx.x);   // reverse within chunk
  int tilebase = tile * 64;

  auto stage = [&](int t, int buf) {
    const unsigned short* sa = S.a[t] + (size_t)(tilebase - S.ro[t]) * S.st[t];
    int st = S.st[t];
#pragma unroll
    for (int q = 0; q < 4; ++q) {
      int c = q * 256 + tid;
      int row = c >> 4, kcl = c & 15;
      int kcg = kcl ^ (row & 7);
      const unsigned short* gp = sa + (size_t)row * st + kcg * 8;
      unsigned short* lp = &Al[buf][(q * 256 + (tid & ~63)) * 8];
      __builtin_amdgcn_global_load_lds(
          (__attribute__((address_space(1))) void*)gp,
          (__attribute__((address_space(3))) void*)lp, 16, 0, 0);
    }
  };

  f32x4 acc[4][NF];
#pragma unroll
  for (int rb = 0; rb < 4; ++rb)
#pragma unroll
    for (int nf = 0; nf < NF; ++nf) {
      f32x4 z = {0.f, 0.f, 0.f, 0.f};
      acc[rb][nf] = z;
    }

  stage(0, 0);
#pragma unroll
  for (int t = 0; t < NK; ++t) {
    __syncthreads();
    if (t + 1 < NK) stage(t + 1, (t + 1) & 1);
    const unsigned short* W = S.w[t];
    const unsigned short* Ab = Al[t & 1];
#pragma unroll
    for (int kk = 0; kk < 4; ++kk) {
      int kc = kk * 4 + kgrp;
      bf16x8 a[4];
#pragma unroll
      for (int rb = 0; rb < 4; ++rb) {
        int arow = rb * 16 + colb;
        a[rb] = *(const bf16x8*)(Ab + (size_t)(arow * 16 + (kc ^ (arow & 7))) * 8);
      }
#pragma unroll
      for (int nf = 0; nf < NF; ++nf) {
        bf16x8 b = *(const bf16x8*)(W + (size_t)(colw + nf * 16 + colb) * 128 + kc * 8);
#pragma unroll
        for (int rb = 0; rb < 4; ++rb)
          acc[rb][nf] = __builtin_amdgcn_mfma_f32_16x16x32_bf16(a[rb], b, acc[rb][nf], 0, 0, 0);
      }
    }
  }

  float bv[NF];
#pragma unroll
  for (int nf = 0; nf < NF; ++nf) bv[nf] = bias[colw + nf * 16 + colb];

  if (EPI == 4 && DOUT == 64) {
    float* Lf = (float*)Al;       // [64][68] padded
    __syncthreads();
#pragma unroll
    for (int rb = 0; rb < 4; ++rb)
#pragma unroll
      for (int i = 0; i < 4; ++i) {
        int row = rb * 16 + kgrp * 4 + i;
        Lf[row * 68 + colw + colb] = acc[rb][0][i] + bv[0];
      }
    __syncthreads();
#pragma unroll
    for (int it = 0; it < 4; ++it) {
      int row = wid * 16 + it * 4 + (lane >> 4);
      float v[4];
#pragma unroll
      for (int j = 0; j < 4; ++j) v[j] = Lf[row * 68 + colb + j * 16];
      float m = fmaxf(fmaxf(v[0], v[1]), fmaxf(v[2], v[3]));
#pragma unroll
      for (int s = 1; s < 16; s <<= 1) m = fmaxf(m, __shfl_xor(m, s));
      float sum = 0.f;
#pragma unroll
      for (int j = 0; j < 4; ++j) sum += __expf(v[j] - m);
#pragma unroll
      for (int s = 1; s < 16; s <<= 1) sum += __shfl_xor(sum, s);
      float lse = m + __logf(sum);
      int grow = tilebase + row;
      if (grow < N) {
#pragma unroll
        for (int j = 0; j < 4; ++j)
          out_f[(size_t)grow * 64 + colb + j * 16] = v[j] - lse;
      }
    }
  } else {
#pragma unroll
    for (int rb = 0; rb < 4; ++rb)
#pragma unroll
      for (int i = 0; i < 4; ++i) {
        int row = tilebase + rb * 16 + kgrp * 4 + i;
        if (row >= N) continue;
#pragma unroll
        for (int nf = 0; nf < NF; ++nf) {
          int col = colw + nf * 16 + colb;
          float v = fmaxf(acc[rb][nf][i] + bv[nf], 0.f);
          out_b[(size_t)row * DOUT + col] = f2b(v);
        }
      }
  }
}

// ---------------- input cast ----------------

__global__ void cast_kernel(const float* __restrict__ in, unsigned short* __restrict__ out,
                            int n4) {
  int stride = gridDim.x * blockDim.x;
  for (int i = blockIdx.x * blockDim.x + threadIdx.x; i < n4; i += stride) {
    float4 v = ((const float4*)in)[i];
    ushort4 o;
    o.x = f2b(v.x); o.y = f2b(v.y); o.z = f2b(v.z); o.w = f2b(v.w);
    ((ushort4*)out)[i] = o;
  }
}

// ---------------- launch ----------------

extern "C" void kernel_launch(void* const* d_in, const int* in_sizes, int n_in,
                              void* d_out, int out_size, void* d_ws, size_t ws_size,
                              hipStream_t stream) {
  const float* x = (const float*)d_in[0];
  const int* eidx = (const int*)d_in[1];
  const int* et = (const int*)d_in[2];
  const float* Wrel1 = (const float*)d_in[3];
  const float* Wroot1 = (const float*)d_in[4];
  const float* b1 = (const float*)d_in[5];
  const float* Wrel2 = (const float*)d_in[6];
  const float* Wroot2 = (const float*)d_in[7];
  const float* b2 = (const float*)d_in[8];
  const float* Wrel3 = (const float*)d_in[9];
  const float* Wroot3 = (const float*)d_in[10];
  const float* b3 = (const float*)d_in[11];

  const int N = in_sizes[0] / 128;    // 100000
  const int E = in_sizes[2];          // 1600000
  const int NT = (N + 63) / 64;       // 1563
  const int NTr = NT * 64;            // 100032
  const int NG = (NT + 127) / 128;    // 13
  const int NBC = 8 * NG;             // 104
  const int* esrc = eidx;
  const int* edst = eidx + E;

  const size_t XB = (size_t)NTr * 128 * 2;   // 25.6 MB

  size_t fixedB = 2 * XB + 2 * ((size_t)9 * 128 * 128 * 2) + (size_t)9 * 64 * 128 * 2 +
                  2 * ((size_t)E * 4) + 2 * ((size_t)8 * NTr * 4) + 8192;
  int CT = 512;                              // chunk tiles; Y chunk = CT*128KB
  while (CT > 64 && fixedB + (size_t)CT * 131072 > ws_size) CT >>= 1;

  char* p = (char*)d_ws;
  auto carve = [&](size_t bytes) {
    void* q = (void*)p;
    p += (bytes + 255) & ~(size_t)255;
    return q;
  };
  unsigned short* bufX0 = (unsigned short*)carve(XB);
  unsigned short* bufX1 = (unsigned short*)carve(XB);
  unsigned short* wt1 = (unsigned short*)carve((size_t)9 * 128 * 128 * 2);
  unsigned short* wt2 = (unsigned short*)carve((size_t)9 * 128 * 128 * 2);
  unsigned short* wt3 = (unsigned short*)carve((size_t)9 * 64 * 128 * 2);
  int* stage = (int*)carve((size_t)E * 4);
  int* srcl = (int*)carve((size_t)E * 4);
  int* lo9 = (int*)carve((size_t)8 * NTr * 4);
  int* len9 = (int*)carve((size_t)8 * NTr * 4);
  int* gh = (int*)carve(512);
  int* gcursor = (int*)carve(512);
  int* cbase = (int*)carve(512);
  unsigned short* Y = (unsigned short*)carve((size_t)CT * 131072);

  // ---- sort v5 (once; reused by all 3 layers) ----
  k_zero2<<<1, 128, 0, stream>>>(gh, 128);
  k_chist<<<512, 256, 0, stream>>>(et, edst, gh, NG, E);
  k_cscan<<<1, 64, 0, stream>>>(gh, gcursor, cbase, NBC, E);
  k_cfill<<<512, 256, 0, stream>>>(et, esrc, edst, gcursor, stage, NG, E);
  k_fine<<<NBC, 1024, 0, stream>>>(cbase, stage, srcl, lo9, len9, NG, NTr);

  // ---- weight prep + input cast ----
  wprep_kernel<<<576, 256, 0, stream>>>(Wrel1, Wroot1, wt1, 128);
  wprep_kernel<<<576, 256, 0, stream>>>(Wrel2, Wroot2, wt2, 128);
  wprep_kernel<<<288, 256, 0, stream>>>(Wrel3, Wroot3, wt3, 64);
  cast_kernel<<<2048, 256, 0, stream>>>(x, bufX0, N * 128 / 4);

  // ---- 3 layers, chunked agg->gemm (Y stays L3-resident, reused per chunk) ----
  auto layer = [&](const unsigned short* xin, const unsigned short* wt,
                   const float* bias, int DOUT, unsigned short* xout, float* fout) {
    for (int c0 = 0; c0 < NT; c0 += CT) {
      int ct = hmin(CT, NT - c0);
      agg_kernel<<<ct * 16, 256, 0, stream>>>((const unsigned*)xin, lo9, len9, srcl,
                                              (unsigned*)Y, N, E, NTr, c0 * 64);
      SrcArr S;
      S.a[0] = xin; S.w[0] = wt + (size_t)8 * DOUT * 128; S.st[0] = 128; S.ro[0] = 0;
      for (int j = 0; j < 8; ++j) {
        S.a[j + 1] = Y + j * 128;
        S.w[j + 1] = wt + (size_t)j * DOUT * 128;
        S.st[j + 1] = 1024;
        S.ro[j + 1] = c0 * 64;
      }
      if (DOUT == 128)
        gemm_lds<128, 3><<<ct, 256, 0, stream>>>(S, bias, xout, (float*)nullptr, N, c0);
      else
        gemm_lds<64, 4><<<ct, 256, 0, stream>>>(S, bias, (unsigned short*)nullptr, fout, N, c0);
    }
  };

  layer(bufX0, wt1, b1, 128, bufX1, nullptr);
  layer(bufX1, wt2, b2, 128, bufX0, nullptr);
  layer(bufX0, wt3, b3, 64, nullptr, (float*)d_out);
}

// Round 22
// 637.431 us; speedup vs baseline: 1.2737x; 1.2737x over previous
//
#include <hip/hip_runtime.h>

// RGCN 3-layer forward, MI355X — decoupled aggregate-then-transform (r19 champion).
// Identity: sum_e x[src_e] @ W_r == (sum_e x[src_e]) @ W_r.
// Final structure after 21 rounds: sort v5 (coarse 104-bin bucket + in-LDS fine
// counting sort), agg (1 wave/dst-row, 8 rels statically unrolled, prefetch-4
// self-clamped, ~4 TB/s mixed-pattern service = measured floor), gemm v4
// (64-row tiles, col-split waves for 4x B-reuse, global_load_lds dbuf + XOR
// swizzle, reverse tile order for L3 LRU), single-pass NRP=8 (K=1152), fused
// bias/ReLU/log-softmax epilogues, in-place layer buffers.
// Refuted levers (r13-r21): NT stores, load guards, scalarization, chunking,
// fusion x5 — gfx950 L3 streams writes through; gather x-refetch is structural.

#define DEVI __device__ __forceinline__

typedef __attribute__((ext_vector_type(8))) short bf16x8;
typedef __attribute__((ext_vector_type(4))) float f32x4;

DEVI unsigned short f2b(float f) {
  unsigned int u = __builtin_bit_cast(unsigned int, f);
  unsigned int r = (u + 0x7FFFu + ((u >> 16) & 1u)) >> 16;
  return (unsigned short)r;
}
DEVI float b2f(unsigned short h) {
  unsigned int u = ((unsigned int)h) << 16;
  return __builtin_bit_cast(float, u);
}
DEVI float lo16f(unsigned v) { return __builtin_bit_cast(float, v << 16); }
DEVI float hifraw(unsigned v) { return __builtin_bit_cast(float, v); }  // hi bf16 + low-bit dust (<0.45% rel)
DEVI int imin(int a, int b) { return a < b ? a : b; }
DEVI int imax(int a, int b) { return a > b ? a : b; }

// ---------------- sort v5: coarse bins = rel*NG + (tile>>7) ----------------

__global__ void k_zero2(int* __restrict__ cnt, int n) {
  int stride = gridDim.x * blockDim.x;
  for (int i = blockIdx.x * blockDim.x + threadIdx.x; i < n; i += stride) cnt[i] = 0;
}

__global__ void k_chist(const int* __restrict__ et, const int* __restrict__ edst,
                        int* __restrict__ gh, int NG, int E) {
  __shared__ int h[128];
  if (threadIdx.x < 128) h[threadIdx.x] = 0;
  __syncthreads();
  int stride = gridDim.x * blockDim.x;
  for (int i = blockIdx.x * blockDim.x + threadIdx.x; i < E; i += stride)
    atomicAdd(&h[(et[i] & 7) * NG + (edst[i] >> 13)], 1);
  __syncthreads();
  if (threadIdx.x < 128) atomicAdd(&gh[threadIdx.x], h[threadIdx.x]);
}

__global__ void k_cscan(const int* __restrict__ gh, int* __restrict__ gcursor,
                        int* __restrict__ cbase, int NBC, int E) {
  if (threadIdx.x == 0) {
    int a = 0;
    for (int b = 0; b < NBC; ++b) { cbase[b] = a; gcursor[b] = a; a += gh[b]; }
    cbase[NBC] = E;
  }
}

__launch_bounds__(256)
__global__ void k_cfill(const int* __restrict__ et, const int* __restrict__ esrc,
                        const int* __restrict__ edst, int* __restrict__ gcursor,
                        int* __restrict__ stage, int NG, int E) {
  __shared__ int h[128], base[128], lc[128];
  int nb = gridDim.x;
  int slice = (E + nb - 1) / nb;
  int lo = blockIdx.x * slice;
  int hi = lo + slice < E ? lo + slice : E;
  int t = threadIdx.x;
  if (t < 128) { h[t] = 0; lc[t] = 0; }
  __syncthreads();
  for (int i = lo + t; i < hi; i += 256)
    atomicAdd(&h[(et[i] & 7) * NG + (edst[i] >> 13)], 1);
  __syncthreads();
  if (t < 128 && h[t] > 0) base[t] = atomicAdd(&gcursor[t], h[t]);
  __syncthreads();
  for (int i = lo + t; i < hi; i += 256) {
    int d = edst[i];
    int tile = d >> 6;
    int bin = (et[i] & 7) * NG + (tile >> 7);
    int p = base[bin] + atomicAdd(&lc[bin], 1);
    stage[p] = ((tile & 127) << 23) | ((d & 63) << 17) | esrc[i];
  }
}

__launch_bounds__(1024)
__global__ void k_fine(const int* __restrict__ cbase, const int* __restrict__ stage,
                       int* __restrict__ srcl, int* __restrict__ lo9,
                       int* __restrict__ len9, int NG, int NTr) {
  __shared__ int h[8192];
  __shared__ int tsum[1024];
  __shared__ int wsum[16];
  int b = blockIdx.x;
  int rel = b / NG, tg = b - rel * NG;
  int lo = cbase[b], hi = cbase[b + 1];
  int t = threadIdx.x;
  for (int k = t; k < 8192; k += 1024) h[k] = 0;
  __syncthreads();
  for (int i = lo + t; i < hi; i += 1024)
    atomicAdd(&h[(stage[i] >> 17) & 0x1FFF], 1);
  __syncthreads();
  int dbase = tg * 8192;
  size_t relbase = (size_t)rel * NTr;
  for (int k = t; k < 8192; k += 1024) {
    int d = dbase + k;
    if (d < NTr) len9[relbase + d] = h[k];
  }
  int loc[8];
  int s = 0;
  int kb = t * 8;
#pragma unroll
  for (int j = 0; j < 8; ++j) { loc[j] = s; s += h[kb + j]; }
  tsum[t] = s;
  __syncthreads();
  int lane = t & 63, w = t >> 6;
  int v = tsum[t];
#pragma unroll
  for (int o = 1; o < 64; o <<= 1) {
    int u = __shfl_up(v, o);
    if (lane >= o) v += u;
  }
  if (lane == 63) wsum[w] = v;
  __syncthreads();
  if (t == 0) {
    int a = 0;
#pragma unroll
    for (int j = 0; j < 16; ++j) { int tmp = wsum[j]; wsum[j] = a; a += tmp; }
  }
  __syncthreads();
  int texcl = v - s + wsum[w];
#pragma unroll
  for (int j = 0; j < 8; ++j) h[kb + j] = texcl + loc[j];
  __syncthreads();
  for (int k = t; k < 8192; k += 1024) {
    int d = dbase + k;
    if (d < NTr) lo9[relbase + d] = lo + h[k];
  }
  __syncthreads();
  for (int i = lo + t; i < hi; i += 1024) {
    int pk = stage[i];
    int key = (pk >> 17) & 0x1FFF;
    int p = atomicAdd(&h[key], 1);
    srcl[lo + p] = pk & 0x1FFFF;
  }
}

// ---------------- weight prep: fp32 [9][128][DOUT] -> bf16 [9][DOUT][128] ----------------

__global__ void wprep_kernel(const float* __restrict__ Wrel, const float* __restrict__ Wroot,
                             unsigned short* __restrict__ wt, int DOUT) {
  int total = 9 * 128 * DOUT;
  int stride = gridDim.x * blockDim.x;
  for (int i = blockIdx.x * blockDim.x + threadIdx.x; i < total; i += stride) {
    int k = i & 127;
    int oo = i >> 7;
    int o = oo % DOUT;
    int rr = oo / DOUT;
    float v = (rr < 8) ? Wrel[((size_t)rr * 128 + k) * DOUT + o]
                       : Wroot[(size_t)k * DOUT + o];
    wt[i] = f2b(v);
  }
}

// ---------------- aggregation: Y slice j = sum over seg(r0+j, d) of x[src] ----
// 1 wave per dst row; NRP rels statically unrolled; first-4 edges prefetched
// UNCONDITIONALLY with self-clamped indices (dup addr for unused slots).

template <int NRP>
__launch_bounds__(256)
__global__ void agg_kernel(const unsigned* __restrict__ x32,   // [NTr][64] dwords
                           const int* __restrict__ lo9, const int* __restrict__ len9,
                           const int* __restrict__ srcl,
                           unsigned* __restrict__ Ydw,         // [NTr][NRP*64] dwords
                           int r0, int N, int E, int NTr) {
  int lane = threadIdx.x & 63;
  int d = (blockIdx.x * blockDim.x + threadIdx.x) >> 6;
  if (d >= N) return;

  int lo[NRP], ln[NRP];
#pragma unroll
  for (int r = 0; r < NRP; ++r) {
    size_t idx = (size_t)(r0 + r) * NTr + d;
    lo[r] = lo9[idx];
    ln[r] = len9[idx];
  }

  // self-clamped prefetch indices: unused j re-reads own last row (dup addr)
  int s[NRP][4];
#pragma unroll
  for (int r = 0; r < NRP; ++r) {
    int lo_c = imin(lo[r], E - 1);
    int jmax = imax(ln[r] - 1, 0);
#pragma unroll
    for (int j = 0; j < 4; ++j)
      s[r][j] = srcl[lo_c + imin(j, jmax)];
  }

  unsigned v[NRP][4];
#pragma unroll
  for (int r = 0; r < NRP; ++r)
#pragma unroll
    for (int j = 0; j < 4; ++j)
      v[r][j] = x32[(size_t)s[r][j] * 64 + lane];

#pragma unroll
  for (int r = 0; r < NRP; ++r) {
    float a0 = 0.f, a1 = 0.f;
#pragma unroll
    for (int j = 0; j < 4; ++j) {
      if (ln[r] > j) { a0 += lo16f(v[r][j]); a1 += hifraw(v[r][j]); }
    }
    if (ln[r] > 4) {
      int i = lo[r] + 4, e = lo[r] + ln[r];
      for (; i + 2 <= e; i += 2) {
        int sA = srcl[i], sB = srcl[i + 1];
        unsigned vA = x32[(size_t)sA * 64 + lane];
        unsigned vB = x32[(size_t)sB * 64 + lane];
        a0 += lo16f(vA) + lo16f(vB);
        a1 += hifraw(vA) + hifraw(vB);
      }
      if (i < e) {
        unsigned vA = x32[(size_t)srcl[i] * 64 + lane];
        a0 += lo16f(vA);
        a1 += hifraw(vA);
      }
    }
    Ydw[(size_t)d * (NRP * 64) + r * 64 + lane] =
        (unsigned)f2b(a0) | ((unsigned)f2b(a1) << 16);
  }
}

// ---------------- LDS-staged GEMM, col-split waves: acc = sum_t A_t @ W_t -------
// Tiles processed in REVERSE order: agg wrote Y forward; L3 holds the newest
// ~200MB, so newest-first reads walk the resident window (LRU-optimal).

struct SrcArr {
  const unsigned short* a[9];
  const unsigned short* w[9];
  int st[9];
};

// EPI: 0=bias->bf16; 1=partial+relu->bf16; 2=partial+lsm->f32;
//      3=bias+relu->bf16; 4=bias+lsm->f32; 5=partial->bf16
template <int DOUT, int NK, int EPI>
__launch_bounds__(256)
__global__ void gemm_lds(SrcArr S, const float* __restrict__ bias,
                         const unsigned short* __restrict__ part,
                         unsigned short* __restrict__ out_b,
                         float* __restrict__ out_f, int N) {
  __shared__ unsigned short Al[2][64 * 128];
  constexpr int NF = (DOUT == 128) ? 2 : 1;
  int tid = threadIdx.x, wid = tid >> 6, lane = tid & 63;
  int colb = lane & 15, kgrp = lane >> 4;
  int colw = wid * 16 * NF;
  int tile = gridDim.x - 1 - blockIdx.x;   // reverse traversal
  int tilebase = tile * 64;

  auto stage = [&](int t, int buf) {
    const unsigned short* sa = S.a[t] + (size_t)tilebase * S.st[t];
    int st = S.st[t];
#pragma unroll
    for (int q = 0; q < 4; ++q) {
      int c = q * 256 + tid;
      int row = c >> 4, kcl = c & 15;
      int kcg = kcl ^ (row & 7);
      const unsigned short* gp = sa + (size_t)row * st + kcg * 8;
      unsigned short* lp = &Al[buf][(q * 256 + (tid & ~63)) * 8];
      __builtin_amdgcn_global_load_lds(
          (__attribute__((address_space(1))) void*)gp,
          (__attribute__((address_space(3))) void*)lp, 16, 0, 0);
    }
  };

  f32x4 acc[4][NF];
#pragma unroll
  for (int rb = 0; rb < 4; ++rb)
#pragma unroll
    for (int nf = 0; nf < NF; ++nf) {
      f32x4 z = {0.f, 0.f, 0.f, 0.f};
      acc[rb][nf] = z;
    }

  stage(0, 0);
#pragma unroll
  for (int t = 0; t < NK; ++t) {
    __syncthreads();
    if (t + 1 < NK) stage(t + 1, (t + 1) & 1);
    const unsigned short* W = S.w[t];
    const unsigned short* Ab = Al[t & 1];
#pragma unroll
    for (int kk = 0; kk < 4; ++kk) {
      int kc = kk * 4 + kgrp;
      bf16x8 a[4];
#pragma unroll
      for (int rb = 0; rb < 4; ++rb) {
        int arow = rb * 16 + colb;
        a[rb] = *(const bf16x8*)(Ab + (size_t)(arow * 16 + (kc ^ (arow & 7))) * 8);
      }
#pragma unroll
      for (int nf = 0; nf < NF; ++nf) {
        bf16x8 b = *(const bf16x8*)(W + (size_t)(colw + nf * 16 + colb) * 128 + kc * 8);
#pragma unroll
        for (int rb = 0; rb < 4; ++rb)
          acc[rb][nf] = __builtin_amdgcn_mfma_f32_16x16x32_bf16(a[rb], b, acc[rb][nf], 0, 0, 0);
      }
    }
  }

  float bv[NF];
  if (EPI == 0 || EPI == 3 || EPI == 4) {
#pragma unroll
    for (int nf = 0; nf < NF; ++nf) bv[nf] = bias[colw + nf * 16 + colb];
  }

  if ((EPI == 2 || EPI == 4) && DOUT == 64) {
    float* Lf = (float*)Al;       // [64][68] padded
    __syncthreads();
#pragma unroll
    for (int rb = 0; rb < 4; ++rb)
#pragma unroll
      for (int i = 0; i < 4; ++i) {
        int row = rb * 16 + kgrp * 4 + i;
        int grow = tilebase + row;
        int rc = grow < N ? grow : 0;
        float v = acc[rb][0][i];
        if (EPI == 4) v += bv[0];
        else v += b2f(part[(size_t)rc * 64 + colw + colb]);
        Lf[row * 68 + colw + colb] = v;
      }
    __syncthreads();
#pragma unroll
    for (int it = 0; it < 4; ++it) {
      int row = wid * 16 + it * 4 + (lane >> 4);
      float v[4];
#pragma unroll
      for (int j = 0; j < 4; ++j) v[j] = Lf[row * 68 + colb + j * 16];
      float m = fmaxf(fmaxf(v[0], v[1]), fmaxf(v[2], v[3]));
#pragma unroll
      for (int s = 1; s < 16; s <<= 1) m = fmaxf(m, __shfl_xor(m, s));
      float sum = 0.f;
#pragma unroll
      for (int j = 0; j < 4; ++j) sum += __expf(v[j] - m);
#pragma unroll
      for (int s = 1; s < 16; s <<= 1) sum += __shfl_xor(sum, s);
      float lse = m + __logf(sum);
      int grow = tilebase + row;
      if (grow < N) {
#pragma unroll
        for (int j = 0; j < 4; ++j)
          out_f[(size_t)grow * 64 + colb + j * 16] = v[j] - lse;
      }
    }
  } else {
#pragma unroll
    for (int rb = 0; rb < 4; ++rb)
#pragma unroll
      for (int i = 0; i < 4; ++i) {
        int row = tilebase + rb * 16 + kgrp * 4 + i;
        bool ok = row < N;
        int rc = ok ? row : 0;
#pragma unroll
        for (int nf = 0; nf < NF; ++nf) {
          int col = colw + nf * 16 + colb;
          float v = acc[rb][nf][i];
          if (EPI == 0 || EPI == 3) v += bv[nf];
          if (EPI == 1 || EPI == 5) v += b2f(part[(size_t)rc * DOUT + col]);
          if (EPI == 1 || EPI == 3) v = fmaxf(v, 0.f);
          if (ok) out_b[(size_t)row * DOUT + col] = f2b(v);
        }
      }
  }
}

template <int DOUT>
static void run_gemm(int NK, int EPI, const SrcArr& S, const float* bias,
                     const unsigned short* part, unsigned short* ob, float* of,
                     int N, int NT, hipStream_t st) {
#define GCALL(nk, epi)                                                        \
  if (NK == nk && EPI == epi) {                                               \
    gemm_lds<DOUT, nk, epi><<<NT, 256, 0, st>>>(S, bias, part, ob, of, N);    \
    return;                                                                   \
  }
  GCALL(9, 3) GCALL(9, 4)
  GCALL(5, 0) GCALL(4, 1) GCALL(4, 2)
  GCALL(3, 0) GCALL(2, 5) GCALL(2, 1) GCALL(2, 2)
#undef GCALL
}

// ---------------- input cast ----------------

__global__ void cast_kernel(const float* __restrict__ in, unsigned short* __restrict__ out,
                            int n4) {
  int stride = gridDim.x * blockDim.x;
  for (int i = blockIdx.x * blockDim.x + threadIdx.x; i < n4; i += stride) {
    float4 v = ((const float4*)in)[i];
    ushort4 o;
    o.x = f2b(v.x); o.y = f2b(v.y); o.z = f2b(v.z); o.w = f2b(v.w);
    ((ushort4*)out)[i] = o;
  }
}

// ---------------- launch ----------------

extern "C" void kernel_launch(void* const* d_in, const int* in_sizes, int n_in,
                              void* d_out, int out_size, void* d_ws, size_t ws_size,
                              hipStream_t stream) {
  const float* x = (const float*)d_in[0];
  const int* eidx = (const int*)d_in[1];
  const int* et = (const int*)d_in[2];
  const float* Wrel1 = (const float*)d_in[3];
  const float* Wroot1 = (const float*)d_in[4];
  const float* b1 = (const float*)d_in[5];
  const float* Wrel2 = (const float*)d_in[6];
  const float* Wroot2 = (const float*)d_in[7];
  const float* b2 = (const float*)d_in[8];
  const float* Wrel3 = (const float*)d_in[9];
  const float* Wroot3 = (const float*)d_in[10];
  const float* b3 = (const float*)d_in[11];

  const int N = in_sizes[0] / 128;    // 100000
  const int E = in_sizes[2];          // 1600000
  const int NT = (N + 63) / 64;       // 1563
  const int NTr = NT * 64;            // 100032
  const int NG = (NT + 127) / 128;    // 13
  const int NBC = 8 * NG;             // 104
  const int* esrc = eidx;
  const int* edst = eidx + E;

  const size_t XB = (size_t)NTr * 128 * 2;   // 25.6 MB

  size_t fixedB = XB + 2 * ((size_t)9 * 128 * 128 * 2) + (size_t)9 * 64 * 128 * 2 +
                  2 * ((size_t)E * 4) + 2 * ((size_t)8 * NTr * 4) + 8192;
  int NRP = 8;
  if (fixedB + 8 * XB > ws_size) NRP = 4;
  if (NRP == 4 && fixedB + XB + 4 * XB > ws_size) NRP = 2;

  char* p = (char*)d_ws;
  auto carve = [&](size_t bytes) {
    void* q = (void*)p;
    p += (bytes + 255) & ~(size_t)255;
    return q;
  };
  unsigned short* bufX = (unsigned short*)carve(XB);
  unsigned short* wt1 = (unsigned short*)carve((size_t)9 * 128 * 128 * 2);
  unsigned short* wt2 = (unsigned short*)carve((size_t)9 * 128 * 128 * 2);
  unsigned short* wt3 = (unsigned short*)carve((size_t)9 * 64 * 128 * 2);
  int* stage = (int*)carve((size_t)E * 4);
  int* srcl = (int*)carve((size_t)E * 4);
  int* lo9 = (int*)carve((size_t)8 * NTr * 4);
  int* len9 = (int*)carve((size_t)8 * NTr * 4);
  int* gh = (int*)carve(512);
  int* gcursor = (int*)carve(512);
  int* cbase = (int*)carve(512);
  unsigned short* part = (unsigned short*)((NRP < 8) ? carve(XB) : nullptr);
  unsigned short* Y = (unsigned short*)carve((size_t)NRP * XB);

  // ---- sort v5 (once; reused by all 3 layers) ----
  k_zero2<<<1, 128, 0, stream>>>(gh, 128);
  k_chist<<<512, 256, 0, stream>>>(et, edst, gh, NG, E);
  k_cscan<<<1, 64, 0, stream>>>(gh, gcursor, cbase, NBC, E);
  k_cfill<<<512, 256, 0, stream>>>(et, esrc, edst, gcursor, stage, NG, E);
  k_fine<<<NBC, 1024, 0, stream>>>(cbase, stage, srcl, lo9, len9, NG, NTr);

  // ---- weight prep + input cast ----
  wprep_kernel<<<576, 256, 0, stream>>>(Wrel1, Wroot1, wt1, 128);
  wprep_kernel<<<576, 256, 0, stream>>>(Wrel2, Wroot2, wt2, 128);
  wprep_kernel<<<288, 256, 0, stream>>>(Wrel3, Wroot3, wt3, 64);
  cast_kernel<<<2048, 256, 0, stream>>>(x, bufX, N * 128 / 4);

  const int ablk = (N * 64 + 255) / 256;
  const int passes = 8 / NRP;

  auto layer = [&](const unsigned short* xin, const unsigned short* wt,
                   const float* bias, int DOUT, unsigned short* xout, float* fout) {
    for (int pidx = 0; pidx < passes; ++pidx) {
      int r0 = pidx * NRP;
      if (NRP == 8)
        agg_kernel<8><<<ablk, 256, 0, stream>>>((const unsigned*)xin, lo9, len9, srcl, (unsigned*)Y, r0, N, E, NTr);
      else if (NRP == 4)
        agg_kernel<4><<<ablk, 256, 0, stream>>>((const unsigned*)xin, lo9, len9, srcl, (unsigned*)Y, r0, N, E, NTr);
      else
        agg_kernel<2><<<ablk, 256, 0, stream>>>((const unsigned*)xin, lo9, len9, srcl, (unsigned*)Y, r0, N, E, NTr);

      SrcArr S;
      int idx = 0;
      if (pidx == 0) {
        S.a[0] = xin; S.w[0] = wt + (size_t)8 * DOUT * 128; S.st[0] = 128;
        idx = 1;
      }
      for (int j = 0; j < NRP; ++j) {
        S.a[idx] = Y + j * 128;
        S.w[idx] = wt + (size_t)(r0 + j) * DOUT * 128;
        S.st[idx] = NRP * 128;
        ++idx;
      }
      int NK = idx;
      int epi;
      bool lastp = (pidx == passes - 1);
      if (pidx == 0 && lastp) epi = (DOUT == 64) ? 4 : 3;
      else if (pidx == 0) epi = 0;
      else if (!lastp) epi = 5;
      else epi = (DOUT == 64) ? 2 : 1;

      unsigned short* ob = lastp ? xout : part;
      if (pidx == 0 && !lastp) ob = part;
      if (DOUT == 128)
        run_gemm<128>(NK, epi, S, bias, part, ob, fout, N, NT, stream);
      else
        run_gemm<64>(NK, epi, S, bias, part, ob, fout, N, NT, stream);
    }
  };

  layer(bufX, wt1, b1, 128, bufX, nullptr);
  layer(bufX, wt2, b2, 128, bufX, nullptr);
  layer(bufX, wt3, b3, 64, nullptr, (float*)d_out);
}